// Round 4
// baseline (314.226 us; speedup 1.0000x reference)
//
#include <hip/hip_runtime.h>
#include <hip/hip_bf16.h>

typedef __bf16 bf16x8 __attribute__((ext_vector_type(8)));
typedef float  f32x4  __attribute__((ext_vector_type(4)));
typedef float  f32x16 __attribute__((ext_vector_type(16)));

#define B_  512
#define DX_ 128
#define H_  512

// ---------------------------------------------------------------------------
// prep (VERBATIM from round 3 -- verified):
//  blocks 0..127   : pack W2 -> 32x32x16 B-frag layout PW2[ks2][nt32][lane][8]
//                    (col = nt32*32 + lane&31, k = ks2*16 + (lane>>5)*8 + j)
//  blocks 128..191 : hx = x@W1x ; hyb = y@W1y + b1 (fp32 out)
// ---------------------------------------------------------------------------
__global__ __launch_bounds__(256) void prep_kernel(
    const float* __restrict__ x, const float* __restrict__ y,
    const float* __restrict__ W1, const float* __restrict__ W2,
    const float* __restrict__ b1,
    __bf16* __restrict__ PW2, float* __restrict__ hx, float* __restrict__ hyb)
{
    int blk = blockIdx.x;
    int tid = threadIdx.x;
    if (blk < 128) {
        int u   = blk * 256 + tid;            // 0..32767
        int ks2 = u >> 10;                    // 0..31  (K=16 steps)
        int rem = u & 1023;
        int nt  = rem >> 6;                   // 0..15  (32-col tiles)
        int l   = rem & 63;
        int k   = ks2 * 16 + ((l >> 5) << 3);
        int col = nt * 32 + (l & 31);
        const float* p = W2 + k * H_ + col;
        bf16x8 v;
        #pragma unroll
        for (int j = 0; j < 8; ++j) v[j] = (__bf16)p[j * H_];
        *(bf16x8*)(PW2 + u * 8) = v;
        return;
    }
    int b    = blk - 128;
    int task = b >> 5;
    int rem  = b & 31;
    int bm   = rem >> 2, bn = rem & 3;
    const float* A  = task ? y : x;
    const float* Wp = W1 + task * DX_ * H_;
    float* outp = task ? hyb : hx;
    int w = tid >> 6, lane = tid & 63;

    f32x4 acc[4][2] = {};
    #pragma unroll
    for (int ks = 0; ks < 4; ++ks) {
        int k0 = ks * 32 + ((lane >> 4) << 3);
        bf16x8 af[4];
        #pragma unroll
        for (int mt = 0; mt < 4; ++mt) {
            int row = bm * 64 + mt * 16 + (lane & 15);
            const float* pa = A + row * DX_ + k0;
            f32x4 q0 = *(const f32x4*)pa;
            f32x4 q1 = *(const f32x4*)(pa + 4);
            #pragma unroll
            for (int j = 0; j < 4; ++j) {
                af[mt][j]     = (__bf16)q0[j];
                af[mt][j + 4] = (__bf16)q1[j];
            }
        }
        #pragma unroll
        for (int nt = 0; nt < 2; ++nt) {
            int col = bn * 128 + (w * 2 + nt) * 16 + (lane & 15);
            const float* pb = Wp + k0 * H_ + col;
            bf16x8 bv;
            #pragma unroll
            for (int j = 0; j < 8; ++j) bv[j] = (__bf16)pb[j * H_];
            #pragma unroll
            for (int mt = 0; mt < 4; ++mt)
                acc[mt][nt] = __builtin_amdgcn_mfma_f32_16x16x32_bf16(af[mt], bv, acc[mt][nt], 0, 0, 0);
        }
    }
    #pragma unroll
    for (int nt = 0; nt < 2; ++nt) {
        int col = bn * 128 + (w * 2 + nt) * 16 + (lane & 15);
        float badd = task ? b1[col] : 0.f;
        #pragma unroll
        for (int mt = 0; mt < 4; ++mt) {
            #pragma unroll
            for (int r = 0; r < 4; ++r) {
                int row = bm * 64 + mt * 16 + ((lane >> 4) << 2) + r;
                outp[row * H_ + col] = acc[mt][nt][r] + badd;
            }
        }
    }
}

// ---------------------------------------------------------------------------
// critic: BARRIER-FREE. One wave = one independent 64-pair-row x 128-col tile.
// A-fragments (relu(hx_i + hy_j) -> bf16) built straight in registers from
// per-lane global loads (L2-hot, 2MB working set); B streams packed from L2.
// Hand-pipelined double buffer (literal indices), s_setprio around MFMA burst,
// no LDS, no __syncthreads. Epilogue: in-wave butterfly reduce + atomicAdd
// partials (4 col-waves per output) into memset-zeroed out; b3/4 folded in.
// ---------------------------------------------------------------------------
__global__ __launch_bounds__(256, 2) void critic_kernel(
    const float* __restrict__ hx, const float* __restrict__ hyb,
    const __bf16* __restrict__ PW2,
    const float* __restrict__ b2, const float* __restrict__ W3,
    const float* __restrict__ b3, float* __restrict__ out)
{
    int tid  = threadIdx.x;
    int lane = tid & 63;
    int W    = blockIdx.x * 4 + (tid >> 6);   // global wave id, 0..16383
    int c    = W & 3;                          // col-slice (128 cols)
    int t    = W >> 2;                         // row-tile  (64 pair-rows)
    int ib   = t >> 6, jb = t & 63;            // 8-i x 8-j tile coords

    int o   = lane >> 5;                       // k-octet within K=16
    int r31 = lane & 31;

    // per-lane A sources: rows i0=(r31>>3), i0+4 (mt=0/1); j = lane&7
    const float* hx0 = hx  + (ib * 8 + (r31 >> 3)) * H_ + o * 8;
    const float* hx1 = hx0 + 4 * H_;
    const float* hyp = hyb + (jb * 8 + (lane & 7)) * H_ + o * 8;
    const __bf16* pb = PW2 + (c * 4) * 512 + lane * 8;   // + s*8192 + nt*512

    f32x16 acc[2][4] = {};

    f32x4  xa[2][2][2];   // [buf][mt][half]
    f32x4  ya[2][2];      // [buf][half]
    bf16x8 bv[2][4];      // [buf][nt]

    auto LOADA = [&](int s, int buf) {
        xa[buf][0][0] = *(const f32x4*)(hx0 + s * 16);
        xa[buf][0][1] = *(const f32x4*)(hx0 + s * 16 + 4);
        xa[buf][1][0] = *(const f32x4*)(hx1 + s * 16);
        xa[buf][1][1] = *(const f32x4*)(hx1 + s * 16 + 4);
        ya[buf][0]    = *(const f32x4*)(hyp + s * 16);
        ya[buf][1]    = *(const f32x4*)(hyp + s * 16 + 4);
    };
    auto LOADB = [&](int s, int buf) {
        const __bf16* p = pb + s * 8192;
        #pragma unroll
        for (int nt = 0; nt < 4; ++nt) bv[buf][nt] = *(const bf16x8*)(p + nt * 512);
    };
    auto COMPUTE = [&](int buf) {
        bf16x8 a[2];
        #pragma unroll
        for (int mt = 0; mt < 2; ++mt)
            #pragma unroll
            for (int j = 0; j < 4; ++j) {
                a[mt][j]     = (__bf16)fmaxf(xa[buf][mt][0][j] + ya[buf][0][j], 0.f);
                a[mt][j + 4] = (__bf16)fmaxf(xa[buf][mt][1][j] + ya[buf][1][j], 0.f);
            }
        __builtin_amdgcn_s_setprio(1);
        #pragma unroll
        for (int nt = 0; nt < 4; ++nt) {
            acc[0][nt] = __builtin_amdgcn_mfma_f32_32x32x16_bf16(a[0], bv[buf][nt], acc[0][nt], 0, 0, 0);
            acc[1][nt] = __builtin_amdgcn_mfma_f32_32x32x16_bf16(a[1], bv[buf][nt], acc[1][nt], 0, 0, 0);
        }
        __builtin_amdgcn_s_setprio(0);
    };

    // software pipeline: issue s+1 loads before computing s (literal buf ids)
    LOADA(0, 0); LOADB(0, 0);
    for (int sp = 0; sp < 16; ++sp) {
        int s0 = sp * 2;
        LOADA(s0 + 1, 1); LOADB(s0 + 1, 1);
        COMPUTE(0);
        if (sp < 15) { LOADA(s0 + 2, 0); LOADB(s0 + 2, 0); }
        COMPUTE(1);
    }

    // epilogue: score[row] += sum_col relu(acc + b2[col]) * W3[col]  (+ b3/4)
    float b2v[4], w3v[4];
    #pragma unroll
    for (int nt = 0; nt < 4; ++nt) {
        int col = c * 128 + nt * 32 + r31;
        b2v[nt] = b2[col];
        w3v[nt] = W3[col];
    }
    float bq = 0.25f * b3[0];
    #pragma unroll
    for (int mt = 0; mt < 2; ++mt) {
        #pragma unroll
        for (int rg = 0; rg < 16; ++rg) {
            float s = 0.f;
            #pragma unroll
            for (int nt = 0; nt < 4; ++nt)
                s += fmaxf(acc[mt][nt][rg] + b2v[nt], 0.f) * w3v[nt];
            s += __shfl_xor(s, 1);
            s += __shfl_xor(s, 2);
            s += __shfl_xor(s, 4);
            s += __shfl_xor(s, 8);
            s += __shfl_xor(s, 16);
            if (r31 == 0) {
                int pl = mt * 32 + (rg & 3) + 8 * (rg >> 2) + (o << 2);  // verified C/D row map
                int i  = ib * 8 + (pl >> 3);
                int j  = jb * 8 + (pl & 7);
                atomicAdd(&out[i * B_ + j], s + bq);
            }
        }
    }
}

// ---------------------------------------------------------------------------
extern "C" void kernel_launch(void* const* d_in, const int* in_sizes, int n_in,
                              void* d_out, int out_size, void* d_ws, size_t ws_size,
                              hipStream_t stream)
{
    const float* x  = (const float*)d_in[0];
    const float* y  = (const float*)d_in[1];
    const float* W1 = (const float*)d_in[2];
    const float* b1 = (const float*)d_in[3];
    const float* W2 = (const float*)d_in[4];
    const float* b2 = (const float*)d_in[5];
    const float* W3 = (const float*)d_in[6];
    const float* b3 = (const float*)d_in[7];
    float* out = (float*)d_out;

    char* ws = (char*)d_ws;
    float*  hx  = (float*)(ws);                    // 1 MB
    float*  hyb = (float*)(ws + 1048576);          // 1 MB
    __bf16* PW2 = (__bf16*)(ws + 2097152);         // 512 KB (end: 2.5 MB)

    hipMemsetAsync(d_out, 0, (size_t)out_size * sizeof(float), stream);
    hipLaunchKernelGGL(prep_kernel, dim3(192), dim3(256), 0, stream,
                       x, y, W1, W2, b1, PW2, hx, hyb);
    hipLaunchKernelGGL(critic_kernel, dim3(4096), dim3(256), 0, stream,
                       hx, hyb, PW2, b2, W3, b3, out);
}